// Round 4
// baseline (556.936 us; speedup 1.0000x reference)
//
#include <hip/hip_runtime.h>

#define IN_DIM 512
#define NBATCH 8192
#define HSTR 136

// ---- v3 geometry: 128 rows x 256-col chunk, BK=64, 4 waves of 64x128 ----
#define V3_BM  128
#define V3_BNT 256
#define V3_BK  64
#define V3_HSTR 264                      // Hsh stride u16 (528B, 132 dw, %32=4 -> spread)
#define V3_H_U16 (V3_BM * V3_HSTR)       // 33792 u16
#define V3_LDS_BYTES (V3_H_U16 * 2)      // 67584 B (B-staging 32KB overlaid at offset 0)

typedef short s16x8 __attribute__((ext_vector_type(8)));
typedef float f32x4 __attribute__((ext_vector_type(4)));

__device__ __forceinline__ unsigned short f2bf(float f) {
    union { float f; unsigned int u; } c;
    c.f = f;
    unsigned int u = c.u;
    u += 0x7fffu + ((u >> 16) & 1u);   // round-to-nearest-even
    return (unsigned short)(u >> 16);
}

__device__ __forceinline__ void gload16(const unsigned short* g, unsigned short* l) {
    __builtin_amdgcn_global_load_lds(
        (const __attribute__((address_space(1))) void*)g,
        (__attribute__((address_space(3))) void*)l,
        16, 0, 0);
}

// ---------------- preprocessing: f32 -> bf16 (+ transpose for Wx, Wp) ----------------

__global__ __launch_bounds__(256)
void conv_inp(const float* __restrict__ in, unsigned short* __restrict__ out) {
    int i = (blockIdx.x * 256 + threadIdx.x) * 8;
    float4 a = *(const float4*)&in[i];
    float4 b = *(const float4*)&in[i + 4];
    union { unsigned short u[8]; s16x8 v; } r;
    r.u[0] = f2bf(a.x); r.u[1] = f2bf(a.y); r.u[2] = f2bf(a.z); r.u[3] = f2bf(a.w);
    r.u[4] = f2bf(b.x); r.u[5] = f2bf(b.y); r.u[6] = f2bf(b.z); r.u[7] = f2bf(b.w);
    *(s16x8*)&out[i] = r.v;
}

// WxT[j][col][k] = bf16(Wx[j][k][col]) via 64x64 LDS tile transpose
__global__ __launch_bounds__(256)
void conv_wxT(const float* __restrict__ Wx, unsigned short* __restrict__ WxT) {
    __shared__ unsigned short T[64][80];
    int j  = blockIdx.y;
    int tr = blockIdx.x >> 3;   // k-tile
    int tc = blockIdx.x & 7;    // col-tile
    const float* src = Wx + (size_t)j * IN_DIM * IN_DIM;
    unsigned short* dst = WxT + (size_t)j * IN_DIM * IN_DIM;
    int tid = threadIdx.x;
    int k  = tid >> 2;
    int c0 = (tid & 3) * 16;
    for (int u = 0; u < 16; u += 4) {
        float4 v = *(const float4*)&src[(size_t)(tr * 64 + k) * IN_DIM + tc * 64 + c0 + u];
        T[c0 + u + 0][k] = f2bf(v.x);
        T[c0 + u + 1][k] = f2bf(v.y);
        T[c0 + u + 2][k] = f2bf(v.z);
        T[c0 + u + 3][k] = f2bf(v.w);
    }
    __syncthreads();
    int c  = tid >> 2;
    int k0 = (tid & 3) * 16;
    for (int u = 0; u < 16; u += 8) {
        s16x8 v = *(const s16x8*)&T[c][k0 + u];
        *(s16x8*)&dst[(size_t)(tc * 64 + c) * IN_DIM + tr * 64 + k0 + u] = v;
    }
}

// WpT[j][w][k] = bf16(Wp[j][k][w])
__global__ __launch_bounds__(256)
void conv_wpT(const float* __restrict__ Wp, unsigned short* __restrict__ WpT) {
    int j = blockIdx.x;
    const float* src = Wp + (size_t)j * IN_DIM * 8;
    unsigned short* dst = WpT + (size_t)j * IN_DIM * 8;
    for (int k = threadIdx.x; k < IN_DIM; k += 256)
        for (int w = 0; w < 8; ++w)
            dst[w * IN_DIM + k] = f2bf(src[k * 8 + w]);
}

// ---------------- v3 fused level kernel: A from global, B via LDS, 64x128/wave ----------------
__global__ __launch_bounds__(256, 2)
void level_v3(const unsigned short* __restrict__ inpB,   // [8192][512] bf16
              const unsigned short* __restrict__ WxT,    // [n][512 col][512 k] bf16
              const float* __restrict__ bx,
              const unsigned short* __restrict__ WpT,    // [n][8][512] bf16
              const float* __restrict__ bp,
              const float* __restrict__ parent,
              int pstride, int poff, int invert_parent,
              float* __restrict__ outp, int ostride)
{
    // lds union: B-staging [256 col][64 k] u16 @ [0,16384) ; Hsh [128][264] u16 @ [0,33792)
    extern __shared__ __align__(16) unsigned short lds[];

    const int tid  = threadIdx.x;
    const int lane = tid & 63;
    const int wv   = tid >> 6;        // 0..3
    const int wr   = wv & 1;          // row half (64 rows)
    const int wc   = wv >> 1;         // col half (128 cols of chunk)
    const int j    = blockIdx.y;
    const int rowBase = blockIdx.x * V3_BM;
    const int lr   = lane & 15;
    const int kg8  = (lane >> 4) * 8;
    const int rg   = (lane >> 4) * 4;

    const unsigned short* WxTj = WxT + (size_t)j * IN_DIM * IN_DIM;
    const unsigned short* WpTj = WpT + (size_t)j * IN_DIM * 8;

    // B staging: thread covers col = i*32 + wv*8 + (lane>>3), k = (lane&7)*8
    const int scol = wv * 8 + (lane >> 3);
    const int sk   = (lane & 7) * 8;
    unsigned short* ldsW = lds + wv * 512;    // wave-uniform base; +lane*16B implicit

    // A fragment source rows (direct global, bf16, 16B aligned)
    const unsigned short* aRow = inpB + (size_t)(rowBase + wr * 64 + lr) * IN_DIM + kg8;

    f32x4 acc2[2] = {};

    #pragma unroll 1
    for (int nt = 0; nt < 2; ++nt) {
        f32x4 acc[4][8] = {};
        const unsigned short* gB = WxTj + (size_t)(nt * V3_BNT + scol) * IN_DIM + sk;

        #pragma unroll 1
        for (int k0 = 0; k0 < IN_DIM; k0 += V3_BK) {
            __syncthreads();   // previous consumers of B region done (incl. prev nt's Hsh use)
            #pragma unroll
            for (int i = 0; i < 8; ++i)
                gload16(gB + (size_t)i * 32 * IN_DIM + k0, ldsW + i * 2048);
            __syncthreads();   // compiler drains vmcnt before barrier -> B ready

            #pragma unroll
            for (int ks = 0; ks < 2; ++ks) {
                s16x8 af[4], bf[8];
                #pragma unroll
                for (int mt = 0; mt < 4; ++mt)
                    af[mt] = *(const s16x8*)(aRow + (size_t)(mt * 16) * IN_DIM + k0 + ks * 32);
                #pragma unroll
                for (int nn = 0; nn < 8; ++nn)
                    bf[nn] = *(const s16x8*)&lds[(wc * 128 + nn * 16 + lr) * V3_BK + ks * 32 + kg8];
                #pragma unroll
                for (int mt = 0; mt < 4; ++mt)
                    #pragma unroll
                    for (int nn = 0; nn < 8; ++nn)
                        acc[mt][nn] = __builtin_amdgcn_mfma_f32_16x16x32_bf16(
                            af[mt], bf[nn], acc[mt][nn], 0, 0, 0);
            }
        }

        __syncthreads();   // all B-frag reads done -> safe to overlay Hsh
        // ---- h = relu(acc + bx) -> Hsh bf16 ----
        #pragma unroll
        for (int nn = 0; nn < 8; ++nn) {
            int ncol = wc * 128 + nn * 16 + lr;
            float bxv = bx[(size_t)j * IN_DIM + nt * V3_BNT + ncol];
            #pragma unroll
            for (int mt = 0; mt < 4; ++mt)
                #pragma unroll
                for (int v = 0; v < 4; ++v) {
                    float h = acc[mt][nn][v] + bxv;
                    h = h > 0.f ? h : 0.f;
                    lds[(wr * 64 + mt * 16 + rg + v) * V3_HSTR + ncol] = f2bf(h);
                }
        }
        __syncthreads();
        // ---- stage-2: logits += Hsh @ WpT ; wave wv owns rows wv*32..+32 ----
        #pragma unroll
        for (int k2 = 0; k2 < 8; ++k2) {
            s16x8 b2 = *(const s16x8*)(WpTj + (size_t)(lr & 7) * IN_DIM + nt * V3_BNT + k2 * 32 + kg8);
            #pragma unroll
            for (int m2 = 0; m2 < 2; ++m2) {
                s16x8 a2 = *(const s16x8*)&lds[(wv * 32 + m2 * 16 + lr) * V3_HSTR + k2 * 32 + kg8];
                acc2[m2] = __builtin_amdgcn_mfma_f32_16x16x32_bf16(a2, b2, acc2[m2], 0, 0, 0);
            }
        }
        // next nt's K-loop leading __syncthreads protects B region from these Hsh reads
    }

    // ---- softmax over 8 cols + parent scale + store ----
    bool valid = lr < 8;
    float bpv = valid ? bp[(size_t)j * 8 + lr] : 0.f;
    #pragma unroll
    for (int m2 = 0; m2 < 2; ++m2) {
        #pragma unroll
        for (int v = 0; v < 4; ++v) {
            float x = acc2[m2][v] + bpv;
            float mx = x;
            for (int d = 1; d < 8; d <<= 1)
                mx = fmaxf(mx, __shfl_xor(mx, d, 64));
            float e = __expf(x - mx);
            float s = e;
            for (int d = 1; d < 8; d <<= 1)
                s += __shfl_xor(s, d, 64);
            float p = e / s;
            int gb = rowBase + wv * 32 + m2 * 16 + rg + v;
            float pv = invert_parent ? (1.f - parent[(size_t)gb * pstride + poff])
                                     : parent[(size_t)gb * pstride + j];
            if (valid)
                outp[(size_t)gb * ostride + j * 8 + lr] = p * pv;
        }
    }
}

// ---------------- round-2 fused level kernel (proven; fallback) ----------------
__global__ __launch_bounds__(256, 2)
void level_fast(const unsigned short* __restrict__ inpB,
                const unsigned short* __restrict__ WxT,
                const float* __restrict__ bx,
                const unsigned short* __restrict__ WpT,
                const float* __restrict__ bp,
                const float* __restrict__ parent,
                int pstride, int poff, int invert_parent,
                float* __restrict__ outp, int ostride)
{
    __shared__ __align__(16) unsigned short lds[128 * HSTR];

    const int tid  = threadIdx.x;
    const int lane = tid & 63;
    const int wv   = tid >> 6;
    const int j    = blockIdx.y;
    const int rowBase = blockIdx.x * 128;
    const int lr  = lane & 15;
    const int kg8 = (lane >> 4) * 8;
    const int rg  = (lane >> 4) * 4;
    const int wm  = (wv & 1) * 64;
    const int wn  = (wv >> 1) * 64;

    const unsigned short* WxTj = WxT + (size_t)j * IN_DIM * IN_DIM;
    const unsigned short* WpTj = WpT + (size_t)j * IN_DIM * 8;

    const int srow  = wv * 32 + (lane >> 2);
    const int sslot = (lane & 3) * 8;

    f32x4 acc2[2] = {};

    for (int nt = 0; nt < 4; ++nt) {
        f32x4 acc[4][4] = {};
        for (int k0 = 0; k0 < IN_DIM; k0 += 32) {
            __syncthreads();
            {
                const unsigned short* ga = inpB + (size_t)(rowBase + srow) * IN_DIM + k0 + sslot;
                const unsigned short* gb = WxTj + (size_t)(nt * 128 + srow) * IN_DIM + k0 + sslot;
                gload16(ga,                &lds[wv * 1024]);
                gload16(ga + 16 * IN_DIM,  &lds[wv * 1024 + 512]);
                gload16(gb,                &lds[4096 + wv * 1024]);
                gload16(gb + 16 * IN_DIM,  &lds[4096 + wv * 1024 + 512]);
            }
            __syncthreads();
            s16x8 af[4], bfr[4];
            for (int mt = 0; mt < 4; ++mt)
                af[mt] = *(const s16x8*)&lds[(wm + mt * 16 + lr) * 32 + kg8];
            for (int nn = 0; nn < 4; ++nn)
                bfr[nn] = *(const s16x8*)&lds[4096 + (wn + nn * 16 + lr) * 32 + kg8];
            for (int mt = 0; mt < 4; ++mt)
                for (int nn = 0; nn < 4; ++nn)
                    acc[mt][nn] = __builtin_amdgcn_mfma_f32_16x16x32_bf16(
                        af[mt], bfr[nn], acc[mt][nn], 0, 0, 0);
        }
        __syncthreads();
        for (int nn = 0; nn < 4; ++nn) {
            int ncol = wn + nn * 16 + lr;
            float bxv = bx[(size_t)j * IN_DIM + nt * 128 + ncol];
            for (int mt = 0; mt < 4; ++mt)
                for (int v = 0; v < 4; ++v) {
                    float h = acc[mt][nn][v] + bxv;
                    h = h > 0.f ? h : 0.f;
                    lds[(wm + mt * 16 + rg + v) * HSTR + ncol] = f2bf(h);
                }
        }
        __syncthreads();
        for (int k2 = 0; k2 < 4; ++k2) {
            int jw = lr & 7;
            s16x8 b2 = *(const s16x8*)(WpTj + jw * IN_DIM + nt * 128 + k2 * 32 + kg8);
            for (int m2 = 0; m2 < 2; ++m2) {
                s16x8 a2 = *(const s16x8*)&lds[(wv * 32 + m2 * 16 + lr) * HSTR + k2 * 32 + kg8];
                acc2[m2] = __builtin_amdgcn_mfma_f32_16x16x32_bf16(a2, b2, acc2[m2], 0, 0, 0);
            }
        }
    }

    bool valid = lr < 8;
    float bpv = valid ? bp[(size_t)j * 8 + lr] : 0.f;
    for (int m2 = 0; m2 < 2; ++m2) {
        for (int v = 0; v < 4; ++v) {
            float x = acc2[m2][v] + bpv;
            float mx = x;
            for (int d = 1; d < 8; d <<= 1)
                mx = fmaxf(mx, __shfl_xor(mx, d, 64));
            float e = __expf(x - mx);
            float s = e;
            for (int d = 1; d < 8; d <<= 1)
                s += __shfl_xor(s, d, 64);
            float p = e / s;
            int gb = rowBase + wv * 32 + m2 * 16 + rg + v;
            float pv = invert_parent ? (1.f - parent[(size_t)gb * pstride + poff])
                                     : parent[(size_t)gb * pstride + j];
            if (valid)
                outp[(size_t)gb * ostride + j * 8 + lr] = p * pv;
        }
    }
}

// ---------------- fallback (f32-direct) level kernel, used if ws too small ----------------
__global__ __launch_bounds__(256, 2)
void level_ref(const float* __restrict__ inp,
               const float* __restrict__ Wx,
               const float* __restrict__ bx,
               const float* __restrict__ Wp,
               const float* __restrict__ bp,
               const float* __restrict__ parent,
               int pstride, int poff, int invert_parent,
               float* __restrict__ outp, int ostride)
{
    __shared__ __align__(16) unsigned short Ash[128][40];
    __shared__ __align__(16) unsigned short Bsh[128][40];
    __shared__ __align__(16) unsigned short Hsh[128][HSTR];
    __shared__ __align__(16) unsigned short WpSh[8][IN_DIM];

    const int tid  = threadIdx.x;
    const int lane = tid & 63;
    const int wv   = tid >> 6;
    const int j    = blockIdx.y;
    const int rowBase = blockIdx.x * 128;
    const int lr = lane & 15;
    const int kg = (lane >> 4) * 8;
    const int rg = (lane >> 4) * 4;
    const int wm = (wv & 1) * 64;
    const int wn = (wv >> 1) * 64;

    const float* WxJ = Wx + (size_t)j * IN_DIM * IN_DIM;
    const float* WpJ = Wp + (size_t)j * IN_DIM * 8;

    for (int i = tid; i < IN_DIM * 2; i += 256) {
        int k  = i >> 1;
        int w4 = (i & 1) * 4;
        float4 v = *(const float4*)&WpJ[k * 8 + w4];
        WpSh[w4 + 0][k] = f2bf(v.x);
        WpSh[w4 + 1][k] = f2bf(v.y);
        WpSh[w4 + 2][k] = f2bf(v.z);
        WpSh[w4 + 3][k] = f2bf(v.w);
    }

    f32x4 acc2[2] = {};

    for (int nt = 0; nt < 4; ++nt) {
        f32x4 acc[4][4] = {};
        for (int k0 = 0; k0 < IN_DIM; k0 += 32) {
            __syncthreads();
            {
                int kk4 = (tid & 7) * 4;
                int rb  = tid >> 3;
                for (int it = 0; it < 4; ++it) {
                    int r = rb + it * 32;
                    float4 v = *(const float4*)&inp[(size_t)(rowBase + r) * IN_DIM + k0 + kk4];
                    unsigned short* dst = &Ash[r][kk4];
                    dst[0] = f2bf(v.x); dst[1] = f2bf(v.y);
                    dst[2] = f2bf(v.z); dst[3] = f2bf(v.w);
                }
            }
            {
                int n4 = (tid & 31) * 4;
                int kb = tid >> 5;
                for (int it = 0; it < 4; ++it) {
                    int kk = kb + it * 8;
                    float4 v = *(const float4*)&WxJ[(size_t)(k0 + kk) * IN_DIM + nt * 128 + n4];
                    Bsh[n4 + 0][kk] = f2bf(v.x);
                    Bsh[n4 + 1][kk] = f2bf(v.y);
                    Bsh[n4 + 2][kk] = f2bf(v.z);
                    Bsh[n4 + 3][kk] = f2bf(v.w);
                }
            }
            __syncthreads();
            s16x8 af[4], bfr[4];
            for (int mt = 0; mt < 4; ++mt)
                af[mt] = *(const s16x8*)&Ash[wm + mt * 16 + lr][kg];
            for (int nn = 0; nn < 4; ++nn)
                bfr[nn] = *(const s16x8*)&Bsh[wn + nn * 16 + lr][kg];
            for (int mt = 0; mt < 4; ++mt)
                for (int nn = 0; nn < 4; ++nn)
                    acc[mt][nn] = __builtin_amdgcn_mfma_f32_16x16x32_bf16(
                        af[mt], bfr[nn], acc[mt][nn], 0, 0, 0);
        }
        __syncthreads();
        for (int nn = 0; nn < 4; ++nn) {
            int ncol = wn + nn * 16 + lr;
            float bxv = bx[(size_t)j * IN_DIM + nt * 128 + ncol];
            for (int mt = 0; mt < 4; ++mt)
                for (int v = 0; v < 4; ++v) {
                    float h = acc[mt][nn][v] + bxv;
                    h = h > 0.f ? h : 0.f;
                    Hsh[wm + mt * 16 + rg + v][ncol] = f2bf(h);
                }
        }
        __syncthreads();
        {
            s16x8 zero = {};
            for (int k2 = 0; k2 < 128; k2 += 32) {
                s16x8 b2 = (lr < 8) ? *(const s16x8*)&WpSh[lr][nt * 128 + k2 + kg] : zero;
                for (int m2 = 0; m2 < 2; ++m2) {
                    s16x8 a2 = *(const s16x8*)&Hsh[wv * 32 + m2 * 16 + lr][k2 + kg];
                    acc2[m2] = __builtin_amdgcn_mfma_f32_16x16x32_bf16(a2, b2, acc2[m2], 0, 0, 0);
                }
            }
        }
    }

    bool valid = lr < 8;
    float bpv = valid ? bp[(size_t)j * 8 + lr] : 0.f;
    for (int m2 = 0; m2 < 2; ++m2) {
        for (int v = 0; v < 4; ++v) {
            float x = acc2[m2][v] + bpv;
            float mx = x;
            for (int d = 1; d < 8; d <<= 1)
                mx = fmaxf(mx, __shfl_xor(mx, d, 64));
            float e = __expf(x - mx);
            float s = e;
            for (int d = 1; d < 8; d <<= 1)
                s += __shfl_xor(s, d, 64);
            float p = e / s;
            int gb = rowBase + wv * 32 + m2 * 16 + rg + v;
            float pv = invert_parent ? (1.f - parent[(size_t)gb * pstride + poff])
                                     : parent[(size_t)gb * pstride + j];
            if (valid)
                outp[(size_t)gb * ostride + j * 8 + lr] = p * pv;
        }
    }
}

// got_event head
__global__ __launch_bounds__(256)
void head_kernel(const float* __restrict__ inp,
                 const float* __restrict__ We,
                 const float* __restrict__ be,
                 float* __restrict__ out)
{
    int row  = blockIdx.x * 4 + (threadIdx.x >> 6);
    int lane = threadIdx.x & 63;
    const float* ip = inp + (size_t)row * IN_DIM;
    float4 a0 = *(const float4*)&ip[lane * 8];
    float4 a1 = *(const float4*)&ip[lane * 8 + 4];
    float4 w0 = *(const float4*)&We[lane * 8];
    float4 w1 = *(const float4*)&We[lane * 8 + 4];
    float s = a0.x*w0.x + a0.y*w0.y + a0.z*w0.z + a0.w*w0.w
            + a1.x*w1.x + a1.y*w1.y + a1.z*w1.z + a1.w*w1.w;
    for (int d = 1; d < 64; d <<= 1)
        s += __shfl_xor(s, d, 64);
    if (lane == 0) {
        float ge = 1.f / (1.f + __expf(-(s + be[0])));
        float og = 1.f - ge;
        out[(size_t)row * 9 + 8] = og;
        out[(size_t)(NBATCH * 9) + (size_t)row * 65 + 64] = og;
        out[(size_t)(NBATCH * 9 + NBATCH * 65) + (size_t)row * 513 + 512] = og;
    }
}

extern "C" void kernel_launch(void* const* d_in, const int* in_sizes, int n_in,
                              void* d_out, int out_size, void* d_ws, size_t ws_size,
                              hipStream_t stream) {
    const float* inp = (const float*)d_in[0];
    const float* Wx0 = (const float*)d_in[1];
    const float* bx0 = (const float*)d_in[2];
    const float* Wp0 = (const float*)d_in[3];
    const float* bp0 = (const float*)d_in[4];
    const float* Wx1 = (const float*)d_in[5];
    const float* bx1 = (const float*)d_in[6];
    const float* Wp1 = (const float*)d_in[7];
    const float* bp1 = (const float*)d_in[8];
    const float* Wx2 = (const float*)d_in[9];
    const float* bx2 = (const float*)d_in[10];
    const float* Wp2 = (const float*)d_in[11];
    const float* bp2 = (const float*)d_in[12];
    const float* We  = (const float*)d_in[13];
    const float* be  = (const float*)d_in[14];
    float* out = (float*)d_out;

    const size_t OUT1 = (size_t)NBATCH * 9;
    const size_t OUT2 = OUT1 + (size_t)NBATCH * 65;

    const size_t INP_E = (size_t)NBATCH * IN_DIM;
    const size_t WX_E  = (size_t)IN_DIM * IN_DIM;
    const size_t WP_E  = (size_t)IN_DIM * 8;
    const size_t NEED  = 2 * (INP_E + 73 * WX_E + 73 * WP_E);

    head_kernel<<<NBATCH / 4, 256, 0, stream>>>(inp, We, be, out);

    dim3 blk(256);
    if (ws_size >= NEED) {
        unsigned short* inpB   = (unsigned short*)d_ws;
        unsigned short* WxTall = inpB + INP_E;
        unsigned short* WpTall = WxTall + 73 * WX_E;

        conv_inp<<<NBATCH * IN_DIM / (256 * 8), 256, 0, stream>>>(inp, inpB);
        conv_wxT<<<dim3(64, 1),  blk, 0, stream>>>(Wx0, WxTall);
        conv_wxT<<<dim3(64, 8),  blk, 0, stream>>>(Wx1, WxTall + 1 * WX_E);
        conv_wxT<<<dim3(64, 64), blk, 0, stream>>>(Wx2, WxTall + 9 * WX_E);
        conv_wpT<<<1,  blk, 0, stream>>>(Wp0, WpTall);
        conv_wpT<<<8,  blk, 0, stream>>>(Wp1, WpTall + 1 * WP_E);
        conv_wpT<<<64, blk, 0, stream>>>(Wp2, WpTall + 9 * WP_E);

        hipError_t rc = hipFuncSetAttribute((const void*)level_v3,
                                            hipFuncAttributeMaxDynamicSharedMemorySize,
                                            V3_LDS_BYTES);
        if (rc == hipSuccess) {
            level_v3<<<dim3(NBATCH / V3_BM, 1), blk, V3_LDS_BYTES, stream>>>(
                inpB, WxTall, bx0, WpTall, bp0, out, 9, 8, 1, out, 9);
            level_v3<<<dim3(NBATCH / V3_BM, 8), blk, V3_LDS_BYTES, stream>>>(
                inpB, WxTall + 1 * WX_E, bx1, WpTall + 1 * WP_E, bp1,
                out, 9, 0, 0, out + OUT1, 65);
            level_v3<<<dim3(NBATCH / V3_BM, 64), blk, V3_LDS_BYTES, stream>>>(
                inpB, WxTall + 9 * WX_E, bx2, WpTall + 9 * WP_E, bp2,
                out + OUT1, 65, 0, 0, out + OUT2, 513);
        } else {
            level_fast<<<dim3(NBATCH / 128, 1), blk, 0, stream>>>(
                inpB, WxTall, bx0, WpTall, bp0, out, 9, 8, 1, out, 9);
            level_fast<<<dim3(NBATCH / 128, 8), blk, 0, stream>>>(
                inpB, WxTall + 1 * WX_E, bx1, WpTall + 1 * WP_E, bp1,
                out, 9, 0, 0, out + OUT1, 65);
            level_fast<<<dim3(NBATCH / 128, 64), blk, 0, stream>>>(
                inpB, WxTall + 9 * WX_E, bx2, WpTall + 9 * WP_E, bp2,
                out + OUT1, 65, 0, 0, out + OUT2, 513);
        }
    } else {
        level_ref<<<dim3(NBATCH / 128, 1), blk, 0, stream>>>(
            inp, Wx0, bx0, Wp0, bp0, out, 9, 8, 1, out, 9);
        level_ref<<<dim3(NBATCH / 128, 8), blk, 0, stream>>>(
            inp, Wx1, bx1, Wp1, bp1, out, 9, 0, 0, out + OUT1, 65);
        level_ref<<<dim3(NBATCH / 128, 64), blk, 0, stream>>>(
            inp, Wx2, bx2, Wp2, bp2, out + OUT1, 65, 0, 0, out + OUT2, 513);
    }
}

// Round 5
// 539.316 us; speedup vs baseline: 1.0327x; 1.0327x over previous
//
#include <hip/hip_runtime.h>

#define IN_DIM 512
#define NBATCH 8192

// ---- v3b geometry: 128 rows x 256-col chunk, BK=64, 4 waves of 64x128 ----
#define V3_BM  128
#define V3_BNT 256
#define V3_BK  64
#define V3_HSTR 260                      // Hsh stride u16: 4-row step = 520dw %32 = 8 -> quarters spread
#define V3_H_U16 (V3_BM * V3_HSTR)       // 33280 u16
#define V3_LDS_BYTES (V3_H_U16 * 2)      // 66560 B (B-staging 32KB overlaid at offset 0)

typedef short s16x8 __attribute__((ext_vector_type(8)));
typedef float f32x4 __attribute__((ext_vector_type(4)));

__device__ __forceinline__ unsigned short f2bf(float f) {
    union { float f; unsigned int u; } c;
    c.f = f;
    unsigned int u = c.u;
    u += 0x7fffu + ((u >> 16) & 1u);   // round-to-nearest-even
    return (unsigned short)(u >> 16);
}

__device__ __forceinline__ void gload16(const unsigned short* g, unsigned short* l) {
    __builtin_amdgcn_global_load_lds(
        (const __attribute__((address_space(1))) void*)g,
        (__attribute__((address_space(3))) void*)l,
        16, 0, 0);
}

// ---------------- preprocessing: f32 -> bf16 (+ transpose / swizzle) ----------------

__global__ __launch_bounds__(256)
void conv_inp(const float* __restrict__ in, unsigned short* __restrict__ out) {
    int i = (blockIdx.x * 256 + threadIdx.x) * 8;
    float4 a = *(const float4*)&in[i];
    float4 b = *(const float4*)&in[i + 4];
    union { unsigned short u[8]; s16x8 v; } r;
    r.u[0] = f2bf(a.x); r.u[1] = f2bf(a.y); r.u[2] = f2bf(a.z); r.u[3] = f2bf(a.w);
    r.u[4] = f2bf(b.x); r.u[5] = f2bf(b.y); r.u[6] = f2bf(b.z); r.u[7] = f2bf(b.w);
    *(s16x8*)&out[i] = r.v;
}

// WxT_ws[j][col][k] = bf16(Wx[j][k_true][col]) stored XOR-swizzled within each 64-k
// slice: 16B chunk index ck is stored at position ck ^ (col & 7). The level kernel
// stages linearly via global_load_lds and applies the same XOR on the ds_read.
__global__ __launch_bounds__(256)
void conv_wxT(const float* __restrict__ Wx, unsigned short* __restrict__ WxT) {
    __shared__ unsigned short T[64][80];
    int j  = blockIdx.y;
    int tr = blockIdx.x >> 3;   // k-tile
    int tc = blockIdx.x & 7;    // col-tile
    const float* src = Wx + (size_t)j * IN_DIM * IN_DIM;
    unsigned short* dst = WxT + (size_t)j * IN_DIM * IN_DIM;
    int tid = threadIdx.x;
    int k  = tid >> 2;
    int c0 = (tid & 3) * 16;
    for (int u = 0; u < 16; u += 4) {
        float4 v = *(const float4*)&src[(size_t)(tr * 64 + k) * IN_DIM + tc * 64 + c0 + u];
        T[c0 + u + 0][k] = f2bf(v.x);
        T[c0 + u + 1][k] = f2bf(v.y);
        T[c0 + u + 2][k] = f2bf(v.z);
        T[c0 + u + 3][k] = f2bf(v.w);
    }
    __syncthreads();
    int c   = tid >> 2;          // col within tile
    int k0b = (tid & 3) * 16;
    for (int u = 0; u < 16; u += 8) {
        int kk = k0b + u;                      // within 64-k slice, multiple of 8
        int ck = (kk >> 3) & 7;
        int kswz = ((ck ^ (c & 7)) << 3);      // swizzled chunk position
        s16x8 v = *(const s16x8*)&T[c][kk];
        *(s16x8*)&dst[(size_t)(tc * 64 + c) * IN_DIM + tr * 64 + kswz] = v;
    }
}

// WpT[j][w][k] = bf16(Wp[j][k][w])   (linear, read straight from global in stage-2)
__global__ __launch_bounds__(256)
void conv_wpT(const float* __restrict__ Wp, unsigned short* __restrict__ WpT) {
    int j = blockIdx.x;
    const float* src = Wp + (size_t)j * IN_DIM * 8;
    unsigned short* dst = WpT + (size_t)j * IN_DIM * 8;
    for (int k = threadIdx.x; k < IN_DIM; k += 256)
        for (int w = 0; w < 8; ++w)
            dst[w * IN_DIM + k] = f2bf(src[k * 8 + w]);
}

// ---------------- v3b fused level kernel: A from global, B via swizzled LDS ----------------
__global__ __launch_bounds__(256, 2)
void level_v3b(const unsigned short* __restrict__ inpB,   // [8192][512] bf16
               const unsigned short* __restrict__ WxT,    // [n][col][k] bf16, chunk-swizzled
               const float* __restrict__ bx,
               const unsigned short* __restrict__ WpT,    // [n][8][512] bf16
               const float* __restrict__ bp,
               const float* __restrict__ parent,
               int pstride, int poff, int invert_parent,
               float* __restrict__ outp, int ostride)
{
    // lds union: B-staging [256 col][64 k] u16 @ [0,32768B) ; Hsh [128][260] u16 @ [0,66560B)
    extern __shared__ __align__(16) unsigned short lds[];

    const int tid  = threadIdx.x;
    const int lane = tid & 63;
    const int wv   = tid >> 6;        // 0..3
    const int wr   = wv & 1;          // row half (64 rows)
    const int wc   = wv >> 1;         // col half (128 cols of chunk)
    const int j    = blockIdx.y;
    const int rowBase = blockIdx.x * V3_BM;
    const int lr   = lane & 15;
    const int grp  = lane >> 4;       // 0..3
    const int kg8  = grp * 8;
    const int rg   = grp * 4;

    const unsigned short* WxTj = WxT + (size_t)j * IN_DIM * IN_DIM;
    const unsigned short* WpTj = WpT + (size_t)j * IN_DIM * 8;

    // B staging: thread covers col = i*32 + wv*8 + (lane>>3), k = (lane&7)*8
    const int scol = wv * 8 + (lane >> 3);
    const int sk   = (lane & 7) * 8;
    unsigned short* ldsW = lds + wv * 512;    // wave-uniform base; +lane*16B implicit

    // swizzled per-lane B-read offsets within a 128-B row (u16 units), ks = 0,1
    const int xor8 = (lr & 7) << 3;
    const int boff0 = (0  + kg8) ^ xor8;
    const int boff1 = (32 + kg8) ^ xor8;

    // A fragment source rows (direct global, bf16, 16B aligned)
    const unsigned short* aRow = inpB + (size_t)(rowBase + wr * 64 + lr) * IN_DIM + kg8;

    f32x4 acc2[2] = {};

    #pragma unroll 1
    for (int nt = 0; nt < 2; ++nt) {
        f32x4 acc[4][8] = {};
        const unsigned short* gB = WxTj + (size_t)(nt * V3_BNT + scol) * IN_DIM + sk;

        #pragma unroll 1
        for (int k0 = 0; k0 < IN_DIM; k0 += V3_BK) {
            __syncthreads();   // previous consumers of B region done
            #pragma unroll
            for (int i = 0; i < 8; ++i)
                gload16(gB + (size_t)i * 32 * IN_DIM + k0, ldsW + i * 2048);
            // hoist A-frag loads: latency drains together with staging at the barrier
            s16x8 af[2][4];
            #pragma unroll
            for (int ks = 0; ks < 2; ++ks)
                #pragma unroll
                for (int mt = 0; mt < 4; ++mt)
                    af[ks][mt] = *(const s16x8*)(aRow + (size_t)(mt * 16) * IN_DIM + k0 + ks * 32);
            __syncthreads();   // B staged (compiler drains vmcnt here)

            #pragma unroll
            for (int ks = 0; ks < 2; ++ks) {
                const int boff = ks ? boff1 : boff0;
                s16x8 bf[8];
                #pragma unroll
                for (int nn = 0; nn < 8; ++nn)
                    bf[nn] = *(const s16x8*)&lds[(wc * 128 + nn * 16 + lr) * V3_BK + boff];
                #pragma unroll
                for (int mt = 0; mt < 4; ++mt)
                    #pragma unroll
                    for (int nn = 0; nn < 8; ++nn)
                        acc[mt][nn] = __builtin_amdgcn_mfma_f32_16x16x32_bf16(
                            af[ks][mt], bf[nn], acc[mt][nn], 0, 0, 0);
            }
        }

        __syncthreads();   // all B-frag reads done -> safe to overlay Hsh
        // ---- h = relu(acc + bx) -> Hsh bf16 ----
        #pragma unroll
        for (int nn = 0; nn < 8; ++nn) {
            int ncol = wc * 128 + nn * 16 + lr;
            float bxv = bx[(size_t)j * IN_DIM + nt * V3_BNT + ncol];
            #pragma unroll
            for (int mt = 0; mt < 4; ++mt)
                #pragma unroll
                for (int v = 0; v < 4; ++v) {
                    float h = acc[mt][nn][v] + bxv;
                    h = h > 0.f ? h : 0.f;
                    lds[(wr * 64 + mt * 16 + rg + v) * V3_HSTR + ncol] = f2bf(h);
                }
        }
        __syncthreads();
        // ---- stage-2: logits += Hsh @ WpT ; wave wv owns rows wv*32..+32 ----
        #pragma unroll
        for (int k2 = 0; k2 < 8; ++k2) {
            s16x8 b2 = *(const s16x8*)(WpTj + (size_t)(lr & 7) * IN_DIM + nt * V3_BNT + k2 * 32 + kg8);
            #pragma unroll
            for (int m2 = 0; m2 < 2; ++m2) {
                s16x8 a2 = *(const s16x8*)&lds[(wv * 32 + m2 * 16 + lr) * V3_HSTR + k2 * 32 + kg8];
                acc2[m2] = __builtin_amdgcn_mfma_f32_16x16x32_bf16(a2, b2, acc2[m2], 0, 0, 0);
            }
        }
        // next nt's leading __syncthreads protects B region from these Hsh reads
    }

    // ---- softmax over 8 cols + parent scale + store ----
    bool valid = lr < 8;
    float bpv = valid ? bp[(size_t)j * 8 + lr] : 0.f;
    #pragma unroll
    for (int m2 = 0; m2 < 2; ++m2) {
        #pragma unroll
        for (int v = 0; v < 4; ++v) {
            float x = acc2[m2][v] + bpv;
            float mx = x;
            for (int d = 1; d < 8; d <<= 1)
                mx = fmaxf(mx, __shfl_xor(mx, d, 64));
            float e = __expf(x - mx);
            float s = e;
            for (int d = 1; d < 8; d <<= 1)
                s += __shfl_xor(s, d, 64);
            float p = e / s;
            int gb = rowBase + wv * 32 + m2 * 16 + rg + v;
            float pv = invert_parent ? (1.f - parent[(size_t)gb * pstride + poff])
                                     : parent[(size_t)gb * pstride + j];
            if (valid)
                outp[(size_t)gb * ostride + j * 8 + lr] = p * pv;
        }
    }
}

// ---------------- fallback (f32-direct) level kernel, used if ws too small ----------------
__global__ __launch_bounds__(256, 2)
void level_ref(const float* __restrict__ inp,
               const float* __restrict__ Wx,
               const float* __restrict__ bx,
               const float* __restrict__ Wp,
               const float* __restrict__ bp,
               const float* __restrict__ parent,
               int pstride, int poff, int invert_parent,
               float* __restrict__ outp, int ostride)
{
    __shared__ __align__(16) unsigned short Ash[128][40];
    __shared__ __align__(16) unsigned short Bsh[128][40];
    __shared__ __align__(16) unsigned short Hsh[128][136];
    __shared__ __align__(16) unsigned short WpSh[8][IN_DIM];

    const int tid  = threadIdx.x;
    const int lane = tid & 63;
    const int wv   = tid >> 6;
    const int j    = blockIdx.y;
    const int rowBase = blockIdx.x * 128;
    const int lr = lane & 15;
    const int kg = (lane >> 4) * 8;
    const int rg = (lane >> 4) * 4;
    const int wm = (wv & 1) * 64;
    const int wn = (wv >> 1) * 64;

    const float* WxJ = Wx + (size_t)j * IN_DIM * IN_DIM;
    const float* WpJ = Wp + (size_t)j * IN_DIM * 8;

    for (int i = tid; i < IN_DIM * 2; i += 256) {
        int k  = i >> 1;
        int w4 = (i & 1) * 4;
        float4 v = *(const float4*)&WpJ[k * 8 + w4];
        WpSh[w4 + 0][k] = f2bf(v.x);
        WpSh[w4 + 1][k] = f2bf(v.y);
        WpSh[w4 + 2][k] = f2bf(v.z);
        WpSh[w4 + 3][k] = f2bf(v.w);
    }

    f32x4 acc2[2] = {};

    for (int nt = 0; nt < 4; ++nt) {
        f32x4 acc[4][4] = {};
        for (int k0 = 0; k0 < IN_DIM; k0 += 32) {
            __syncthreads();
            {
                int kk4 = (tid & 7) * 4;
                int rb  = tid >> 3;
                for (int it = 0; it < 4; ++it) {
                    int r = rb + it * 32;
                    float4 v = *(const float4*)&inp[(size_t)(rowBase + r) * IN_DIM + k0 + kk4];
                    unsigned short* dst = &Ash[r][kk4];
                    dst[0] = f2bf(v.x); dst[1] = f2bf(v.y);
                    dst[2] = f2bf(v.z); dst[3] = f2bf(v.w);
                }
            }
            {
                int n4 = (tid & 31) * 4;
                int kb = tid >> 5;
                for (int it = 0; it < 4; ++it) {
                    int kk = kb + it * 8;
                    float4 v = *(const float4*)&WxJ[(size_t)(k0 + kk) * IN_DIM + nt * 128 + n4];
                    Bsh[n4 + 0][kk] = f2bf(v.x);
                    Bsh[n4 + 1][kk] = f2bf(v.y);
                    Bsh[n4 + 2][kk] = f2bf(v.z);
                    Bsh[n4 + 3][kk] = f2bf(v.w);
                }
            }
            __syncthreads();
            s16x8 af[4], bfr[4];
            for (int mt = 0; mt < 4; ++mt)
                af[mt] = *(const s16x8*)&Ash[wm + mt * 16 + lr][kg];
            for (int nn = 0; nn < 4; ++nn)
                bfr[nn] = *(const s16x8*)&Bsh[wn + nn * 16 + lr][kg];
            for (int mt = 0; mt < 4; ++mt)
                for (int nn = 0; nn < 4; ++nn)
                    acc[mt][nn] = __builtin_amdgcn_mfma_f32_16x16x32_bf16(
                        af[mt], bfr[nn], acc[mt][nn], 0, 0, 0);
        }
        __syncthreads();
        for (int nn = 0; nn < 4; ++nn) {
            int ncol = wn + nn * 16 + lr;
            float bxv = bx[(size_t)j * IN_DIM + nt * 128 + ncol];
            for (int mt = 0; mt < 4; ++mt)
                for (int v = 0; v < 4; ++v) {
                    float h = acc[mt][nn][v] + bxv;
                    h = h > 0.f ? h : 0.f;
                    Hsh[wm + mt * 16 + rg + v][ncol] = f2bf(h);
                }
        }
        __syncthreads();
        {
            s16x8 zero = {};
            for (int k2 = 0; k2 < 128; k2 += 32) {
                s16x8 b2 = (lr < 8) ? *(const s16x8*)&WpSh[lr][nt * 128 + k2 + kg] : zero;
                for (int m2 = 0; m2 < 2; ++m2) {
                    s16x8 a2 = *(const s16x8*)&Hsh[wv * 32 + m2 * 16 + lr][k2 + kg];
                    acc2[m2] = __builtin_amdgcn_mfma_f32_16x16x32_bf16(a2, b2, acc2[m2], 0, 0, 0);
                }
            }
        }
    }

    bool valid = lr < 8;
    float bpv = valid ? bp[(size_t)j * 8 + lr] : 0.f;
    for (int m2 = 0; m2 < 2; ++m2) {
        for (int v = 0; v < 4; ++v) {
            float x = acc2[m2][v] + bpv;
            float mx = x;
            for (int d = 1; d < 8; d <<= 1)
                mx = fmaxf(mx, __shfl_xor(mx, d, 64));
            float e = __expf(x - mx);
            float s = e;
            for (int d = 1; d < 8; d <<= 1)
                s += __shfl_xor(s, d, 64);
            float p = e / s;
            int gb = rowBase + wv * 32 + m2 * 16 + rg + v;
            float pv = invert_parent ? (1.f - parent[(size_t)gb * pstride + poff])
                                     : parent[(size_t)gb * pstride + j];
            if (valid)
                outp[(size_t)gb * ostride + j * 8 + lr] = p * pv;
        }
    }
}

// got_event head
__global__ __launch_bounds__(256)
void head_kernel(const float* __restrict__ inp,
                 const float* __restrict__ We,
                 const float* __restrict__ be,
                 float* __restrict__ out)
{
    int row  = blockIdx.x * 4 + (threadIdx.x >> 6);
    int lane = threadIdx.x & 63;
    const float* ip = inp + (size_t)row * IN_DIM;
    float4 a0 = *(const float4*)&ip[lane * 8];
    float4 a1 = *(const float4*)&ip[lane * 8 + 4];
    float4 w0 = *(const float4*)&We[lane * 8];
    float4 w1 = *(const float4*)&We[lane * 8 + 4];
    float s = a0.x*w0.x + a0.y*w0.y + a0.z*w0.z + a0.w*w0.w
            + a1.x*w1.x + a1.y*w1.y + a1.z*w1.z + a1.w*w1.w;
    for (int d = 1; d < 64; d <<= 1)
        s += __shfl_xor(s, d, 64);
    if (lane == 0) {
        float ge = 1.f / (1.f + __expf(-(s + be[0])));
        float og = 1.f - ge;
        out[(size_t)row * 9 + 8] = og;
        out[(size_t)(NBATCH * 9) + (size_t)row * 65 + 64] = og;
        out[(size_t)(NBATCH * 9 + NBATCH * 65) + (size_t)row * 513 + 512] = og;
    }
}

extern "C" void kernel_launch(void* const* d_in, const int* in_sizes, int n_in,
                              void* d_out, int out_size, void* d_ws, size_t ws_size,
                              hipStream_t stream) {
    const float* inp = (const float*)d_in[0];
    const float* Wx0 = (const float*)d_in[1];
    const float* bx0 = (const float*)d_in[2];
    const float* Wp0 = (const float*)d_in[3];
    const float* bp0 = (const float*)d_in[4];
    const float* Wx1 = (const float*)d_in[5];
    const float* bx1 = (const float*)d_in[6];
    const float* Wp1 = (const float*)d_in[7];
    const float* bp1 = (const float*)d_in[8];
    const float* Wx2 = (const float*)d_in[9];
    const float* bx2 = (const float*)d_in[10];
    const float* Wp2 = (const float*)d_in[11];
    const float* bp2 = (const float*)d_in[12];
    const float* We  = (const float*)d_in[13];
    const float* be  = (const float*)d_in[14];
    float* out = (float*)d_out;

    const size_t OUT1 = (size_t)NBATCH * 9;
    const size_t OUT2 = OUT1 + (size_t)NBATCH * 65;

    const size_t INP_E = (size_t)NBATCH * IN_DIM;
    const size_t WX_E  = (size_t)IN_DIM * IN_DIM;
    const size_t WP_E  = (size_t)IN_DIM * 8;
    const size_t NEED  = 2 * (INP_E + 73 * WX_E + 73 * WP_E);

    head_kernel<<<NBATCH / 4, 256, 0, stream>>>(inp, We, be, out);

    dim3 blk(256);
    bool fast = false;
    if (ws_size >= NEED) {
        hipError_t rc = hipFuncSetAttribute((const void*)level_v3b,
                                            hipFuncAttributeMaxDynamicSharedMemorySize,
                                            V3_LDS_BYTES);
        fast = (rc == hipSuccess);
    }

    if (fast) {
        unsigned short* inpB   = (unsigned short*)d_ws;
        unsigned short* WxTall = inpB + INP_E;
        unsigned short* WpTall = WxTall + 73 * WX_E;

        conv_inp<<<NBATCH * IN_DIM / (256 * 8), 256, 0, stream>>>(inp, inpB);
        conv_wxT<<<dim3(64, 1),  blk, 0, stream>>>(Wx0, WxTall);
        conv_wxT<<<dim3(64, 8),  blk, 0, stream>>>(Wx1, WxTall + 1 * WX_E);
        conv_wxT<<<dim3(64, 64), blk, 0, stream>>>(Wx2, WxTall + 9 * WX_E);
        conv_wpT<<<1,  blk, 0, stream>>>(Wp0, WpTall);
        conv_wpT<<<8,  blk, 0, stream>>>(Wp1, WpTall + 1 * WP_E);
        conv_wpT<<<64, blk, 0, stream>>>(Wp2, WpTall + 9 * WP_E);

        level_v3b<<<dim3(NBATCH / V3_BM, 1), blk, V3_LDS_BYTES, stream>>>(
            inpB, WxTall, bx0, WpTall, bp0, out, 9, 8, 1, out, 9);
        level_v3b<<<dim3(NBATCH / V3_BM, 8), blk, V3_LDS_BYTES, stream>>>(
            inpB, WxTall + 1 * WX_E, bx1, WpTall + 1 * WP_E, bp1,
            out, 9, 0, 0, out + OUT1, 65);
        level_v3b<<<dim3(NBATCH / V3_BM, 64), blk, V3_LDS_BYTES, stream>>>(
            inpB, WxTall + 9 * WX_E, bx2, WpTall + 9 * WP_E, bp2,
            out + OUT1, 65, 0, 0, out + OUT2, 513);
    } else {
        level_ref<<<dim3(NBATCH / 128, 1), blk, 0, stream>>>(
            inp, Wx0, bx0, Wp0, bp0, out, 9, 8, 1, out, 9);
        level_ref<<<dim3(NBATCH / 128, 8), blk, 0, stream>>>(
            inp, Wx1, bx1, Wp1, bp1, out, 9, 0, 0, out + OUT1, 65);
        level_ref<<<dim3(NBATCH / 128, 64), blk, 0, stream>>>(
            inp, Wx2, bx2, Wp2, bp2, out + OUT1, 65, 0, 0, out + OUT2, 513);
    }
}